// Round 5
// baseline (5256.524 us; speedup 1.0000x reference)
//
#include <hip/hip_runtime.h>
#include <stdint.h>

#define TSTEPS 512
#define BATCH  64
#define HDIM   512
#define GATE   2048
#define ACTMAT (BATCH * HDIM)   // 32768 activations per timestep matrix
#define SENT   0xFFFFFFFFu      // bf16 NaN-pair sentinel; |h|<1 so never produced

typedef __attribute__((ext_vector_type(8))) short bf16x8;
typedef __attribute__((ext_vector_type(4))) float f32x4;
typedef __attribute__((ext_vector_type(4))) uint32_t u32x4;

__device__ __forceinline__ unsigned short f2bf(float f) {
  union { float f; uint32_t u; } v; v.f = f;
  uint32_t r = v.u + 0x7FFFu + ((v.u >> 16) & 1u);   // RNE
  return (unsigned short)(r >> 16);
}
__device__ __forceinline__ float bf2f(unsigned short s) {
  union { uint32_t u; float f; } v; v.u = ((uint32_t)s) << 16;
  return v.f;
}
__device__ __forceinline__ float fsigmoid(float x) {
  return 1.0f / (1.0f + __expf(-x));
}

// ---------------- pre-kernels ----------------

// Fill h histories with sentinel; t=0 slice (first 4096 16B-units) = 0 (valid initial h).
__global__ void init_h(unsigned short* h0, unsigned short* h1) {
  size_t u = (size_t)blockIdx.x * blockDim.x + threadIdx.x;   // 16B unit index
  u32x4 v;
  if (u < (ACTMAT * 2 / 16)) v = (u32x4){0u, 0u, 0u, 0u};
  else                       v = (u32x4){SENT, SENT, SENT, SENT};
  ((u32x4*)h0)[u] = v;
  ((u32x4*)h1)[u] = v;
}

__global__ void convert_x(const float* __restrict__ x, unsigned short* __restrict__ xb) {
  size_t i = (size_t)(blockIdx.x * blockDim.x + threadIdx.x) * 4;
  float4 v = *(const float4*)(x + i);
  ushort4 o = make_ushort4(f2bf(v.x), f2bf(v.y), f2bf(v.z), f2bf(v.w));
  *(ushort4*)(xb + i) = o;
}

// Fuse [Wi | Wh] into [GATE][1024]; split each weight into bf16 hi + lo residual.
__global__ void split_w(const float* __restrict__ Wi, const float* __restrict__ Wh,
                        unsigned short* __restrict__ Whi, unsigned short* __restrict__ Wlo) {
  int i = blockIdx.x * blockDim.x + threadIdx.x;     // over GATE*1024
  int G = i >> 10, k = i & 1023;
  float w = (k < 512) ? Wi[((size_t)G << 9) + k] : Wh[((size_t)G << 9) + (k - 512)];
  unsigned short hi = f2bf(w);
  Whi[i] = hi;
  Wlo[i] = f2bf(w - bf2f(hi));
}

// ---------------- persistent recurrence kernel ----------------
// 128 WGs x 256 threads: blockIdx>>6 = layer, blockIdx&63 = slice (8 h-cols, 32 gate rows).
// Transposed GEMM: D[n][b] = sum_k W[n][k]*Act[b][k] via mfma(A=W_frag, B=Act_frag).
// Gate-row ordering G(n) = (n&3)*512 + j0 + 2*((n&15)>>2) + (n>>4): lane's 8 acc regs =
// all 4 gate quadrants of (b, j) and (b, j+1) -> zero-shuffle epilogue, one packed 4B
// h-store per lane. SYNC = DATA-AS-FLAG: h buffers pre-filled with SENT; producers just
// store packed dwords (L1/L2-bypass, meet at coherent L3); consumers speculatively issue
// bypass loads, hide the round trip under independent MFMA work, then vmcnt(0)+sentinel
// check, re-issuing while any lane sees SENT. No flags, no fences, no barriers in loop.

__global__ __launch_bounds__(256, 1)
void sublstm_persistent(const unsigned short* __restrict__ xb,
                        unsigned short* h0, unsigned short* h1,
                        const unsigned short* __restrict__ W0hi, const unsigned short* __restrict__ W0lo,
                        const unsigned short* __restrict__ W1hi, const unsigned short* __restrict__ W1lo,
                        const float* __restrict__ bi0, const float* __restrict__ bi1,
                        float* __restrict__ out)
{
  __shared__ unsigned short wlds[2][32][1024];       // 128 KiB: [hi/lo][n][k]

  const int wg    = blockIdx.x;
  const int layer = wg >> 6;
  const int slice = wg & 63;
  const int j0    = slice << 3;                      // first owned h-column
  const int tid   = threadIdx.x;
  const int lane  = tid & 63;
  const int wv    = tid >> 6;                        // wave 0..3 (b-tile)

  const unsigned short* Whi = layer ? W1hi : W0hi;
  const unsigned short* Wlo = layer ? W1lo : W0lo;
  const float* bi = layer ? bi1 : bi0;

  // stage weight slice into LDS (16B units, unit index XOR-swizzled by n&15)
  for (int idx = tid; idx < 8192; idx += 256) {
    int p = idx >> 12;                               // hi/lo panel
    int n = (idx >> 7) & 31;                         // local gate row
    int u = idx & 127;                               // 16B unit within row
    int G = ((n & 3) << 9) + j0 + ((((n & 15) >> 2)) << 1) + (n >> 4);
    const unsigned short* s = (p ? Wlo : Whi) + ((size_t)G << 10) + ((size_t)u << 3);
    *(uint4*)&wlds[p][n][(u ^ (n & 15)) << 3] = *(const uint4*)s;
  }
  __syncthreads();

  const int c15 = lane & 15;
  const int g4  = lane >> 4;
  const int n0 = c15, n1 = 16 + c15;
  const int sw = c15;                                // XOR swizzle key
  const int b    = (wv << 4) + c15;                  // batch row this lane owns
  const int jcol0 = j0 + (g4 << 1);                  // even h-col; pair (jcol0, jcol0+1)
  const size_t arow = (size_t)b * HDIM;
  const size_t hoff0 = arow + jcol0;

  const float b00 = bi[jcol0],        b01 = bi[512 + jcol0];
  const float b02 = bi[1024 + jcol0], b03 = bi[1536 + jcol0];
  const float b10 = bi[jcol0 + 1],        b11 = bi[512 + jcol0 + 1];
  const float b12 = bi[1024 + jcol0 + 1], b13 = bi[1536 + jcol0 + 1];

  float c0 = 0.0f, c1 = 0.0f;                        // cell state, in regs all 512 steps

#define CONSUME(R, KK, UB) do {                                                        \
    bf16x8 a = __builtin_bit_cast(bf16x8, (R));                                        \
    int u_ = ((UB) + ((KK) << 2) + g4) ^ sw;                                           \
    bf16x8 wh0 = *(const bf16x8*)&wlds[0][n0][u_ << 3];                                \
    bf16x8 wl0 = *(const bf16x8*)&wlds[1][n0][u_ << 3];                                \
    bf16x8 wh1 = *(const bf16x8*)&wlds[0][n1][u_ << 3];                                \
    bf16x8 wl1 = *(const bf16x8*)&wlds[1][n1][u_ << 3];                                \
    acc0 = __builtin_amdgcn_mfma_f32_16x16x32_bf16(wh0, a, acc0, 0, 0, 0);             \
    acc0 = __builtin_amdgcn_mfma_f32_16x16x32_bf16(wl0, a, acc0, 0, 0, 0);             \
    acc1 = __builtin_amdgcn_mfma_f32_16x16x32_bf16(wh1, a, acc1, 0, 0, 0);             \
    acc1 = __builtin_amdgcn_mfma_f32_16x16x32_bf16(wl1, a, acc1, 0, 0, 0);             \
  } while (0)

#define CONSUME_ALL(P, UB)                                                             \
    CONSUME(P##0, 0, UB);  CONSUME(P##1, 1, UB);  CONSUME(P##2, 2, UB);                \
    CONSUME(P##3, 3, UB);  CONSUME(P##4, 4, UB);  CONSUME(P##5, 5, UB);                \
    CONSUME(P##6, 6, UB);  CONSUME(P##7, 7, UB);  CONSUME(P##8, 8, UB);                \
    CONSUME(P##9, 9, UB);  CONSUME(P##10, 10, UB); CONSUME(P##11, 11, UB);             \
    CONSUME(P##12, 12, UB); CONSUME(P##13, 13, UB); CONSUME(P##14, 14, UB);            \
    CONSUME(P##15, 15, UB)

#define LD1(R, OFFTOK, HP)                                                             \
    asm volatile("global_load_dwordx4 %0, %1, off " OFFTOK " sc0 sc1"                  \
                 : "=v"(R) : "v"(HP) : "memory")

#define ISSUE16(HP, P) do {                                                            \
    LD1(P##0, "", HP);            LD1(P##1, "offset:64", HP);                          \
    LD1(P##2, "offset:128", HP);  LD1(P##3, "offset:192", HP);                         \
    LD1(P##4, "offset:256", HP);  LD1(P##5, "offset:320", HP);                         \
    LD1(P##6, "offset:384", HP);  LD1(P##7, "offset:448", HP);                         \
    LD1(P##8, "offset:512", HP);  LD1(P##9, "offset:576", HP);                         \
    LD1(P##10, "offset:640", HP); LD1(P##11, "offset:704", HP);                        \
    LD1(P##12, "offset:768", HP); LD1(P##13, "offset:832", HP);                        \
    LD1(P##14, "offset:896", HP); LD1(P##15, "offset:960", HP);                        \
  } while (0)

#define BAD1(R) ((R[0] == SENT) | (R[1] == SENT) | (R[2] == SENT) | (R[3] == SENT))

#define VALIDATE(HP, P) do {                                                           \
    for (;;) {                                                                         \
      asm volatile("s_waitcnt vmcnt(0)" ::: "memory");                                 \
      __builtin_amdgcn_sched_barrier(0);                                               \
      int bad_ = BAD1(P##0) | BAD1(P##1) | BAD1(P##2) | BAD1(P##3) |                   \
                 BAD1(P##4) | BAD1(P##5) | BAD1(P##6) | BAD1(P##7) |                   \
                 BAD1(P##8) | BAD1(P##9) | BAD1(P##10) | BAD1(P##11) |                 \
                 BAD1(P##12) | BAD1(P##13) | BAD1(P##14) | BAD1(P##15);                \
      if (!__any(bad_)) break;                                                         \
      ISSUE16(HP, P);                                                                  \
    }                                                                                  \
    __builtin_amdgcn_sched_barrier(0);                                                 \
  } while (0)

// x half: plain cached loads (xb is read-only input, L2-resident per XCD)
#define KHALF_X(AP) do {                                                               \
    const unsigned short* ap_ = (AP) + arow + (g4 << 3);                               \
    _Pragma("unroll")                                                                  \
    for (int kk = 0; kk < 16; ++kk) {                                                  \
      u32x4 rr = *(const u32x4*)(ap_ + (kk << 5));                                     \
      CONSUME(rr, kk, 0);                                                              \
    }                                                                                  \
  } while (0)

#define EPILOGUE(T) do {                                                               \
    unsigned short* hn = (layer ? h1 : h0) + (size_t)((T) + 1) * ACTMAT;               \
    float gi0 = fsigmoid(acc0[0] + b00), go0 = fsigmoid(acc0[1] + b01);                \
    float gz0 = fsigmoid(acc0[2] + b02), gf0 = fsigmoid(acc0[3] + b03);                \
    c0 = c0 * gf0 + gz0 - gi0;                                                         \
    float hv0 = fsigmoid(c0) - go0;                                                    \
    float gi1 = fsigmoid(acc1[0] + b10), go1 = fsigmoid(acc1[1] + b11);                \
    float gz1 = fsigmoid(acc1[2] + b12), gf1 = fsigmoid(acc1[3] + b13);                \
    c1 = c1 * gf1 + gz1 - gi1;                                                         \
    float hv1 = fsigmoid(c1) - go1;                                                    \
    uint32_t hw = (uint32_t)f2bf(hv0) | ((uint32_t)f2bf(hv1) << 16);                   \
    __hip_atomic_store((uint32_t*)(hn + hoff0), hw, __ATOMIC_RELAXED,                  \
                       __HIP_MEMORY_SCOPE_AGENT);                                      \
    if (layer) {                                                                       \
      float* outp = out + (size_t)(T) * ACTMAT;                                        \
      *(float2*)(outp + hoff0) = make_float2(hv0, hv1);                                \
    }                                                                                  \
  } while (0)

  if (layer == 0) {
    for (int t = 0; t < TSTEPS; ++t) {
      f32x4 acc0 = {}, acc1 = {};
      u32x4 ra0, ra1, ra2, ra3, ra4, ra5, ra6, ra7,
            ra8, ra9, ra10, ra11, ra12, ra13, ra14, ra15;
      const unsigned short* hp = h0 + (size_t)t * ACTMAT + arow + (g4 << 3);
      ISSUE16(hp, ra);                               // speculative: hide RT under x-half
      KHALF_X(xb + (size_t)t * ACTMAT);              // independent work (64 MFMAs)
      VALIDATE(hp, ra);                              // sentinel check, re-issue if stale
      CONSUME_ALL(ra, 64);
      EPILOGUE(t);
    }
  } else {
    for (int t = 0; t < TSTEPS; ++t) {
      f32x4 acc0 = {}, acc1 = {};
      u32x4 ra0, ra1, ra2, ra3, ra4, ra5, ra6, ra7,
            ra8, ra9, ra10, ra11, ra12, ra13, ra14, ra15;
      u32x4 rb0, rb1, rb2, rb3, rb4, rb5, rb6, rb7,
            rb8, rb9, rb10, rb11, rb12, rb13, rb14, rb15;
      const unsigned short* hpA = h1 + (size_t)t * ACTMAT + arow + (g4 << 3);
      const unsigned short* hpB = h0 + (size_t)(t + 1) * ACTMAT + arow + (g4 << 3);
      ISSUE16(hpA, ra);                              // own h1[t]: almost always landed
      ISSUE16(hpB, rb);                              // layer0's h0[t+1]: the late one
      VALIDATE(hpA, ra);
      CONSUME_ALL(ra, 64);                           // 64 MFMAs hide hpB's round trip
      VALIDATE(hpB, rb);
      CONSUME_ALL(rb, 0);
      EPILOGUE(t);
    }
  }
#undef CONSUME
#undef CONSUME_ALL
#undef LD1
#undef ISSUE16
#undef BAD1
#undef VALIDATE
#undef KHALF_X
#undef EPILOGUE
}

// ---------------- launch ----------------

extern "C" void kernel_launch(void* const* d_in, const int* in_sizes, int n_in,
                              void* d_out, int out_size, void* d_ws, size_t ws_size,
                              hipStream_t stream) {
  (void)in_sizes; (void)n_in; (void)out_size; (void)ws_size;
  const float* x   = (const float*)d_in[0];
  const float* Wi0 = (const float*)d_in[1];
  const float* bi0 = (const float*)d_in[2];
  const float* Wh0 = (const float*)d_in[3];
  const float* Wi1 = (const float*)d_in[4];
  const float* bi1 = (const float*)d_in[5];
  const float* Wh1 = (const float*)d_in[6];
  float* out = (float*)d_out;

  char* ws = (char*)d_ws;
  size_t off = 0;
  auto take = [&](size_t bytes) -> void* {
    void* p = ws + off;
    off += (bytes + 255) & ~(size_t)255;
    return p;
  };
  unsigned short* xb   = (unsigned short*)take((size_t)TSTEPS * ACTMAT * 2);        // 33.5 MB
  unsigned short* h0   = (unsigned short*)take((size_t)(TSTEPS + 1) * ACTMAT * 2);  // 33.6 MB
  unsigned short* h1   = (unsigned short*)take((size_t)(TSTEPS + 1) * ACTMAT * 2);  // 33.6 MB
  unsigned short* W0hi = (unsigned short*)take((size_t)GATE * 1024 * 2);            // 4 MB x4
  unsigned short* W0lo = (unsigned short*)take((size_t)GATE * 1024 * 2);
  unsigned short* W1hi = (unsigned short*)take((size_t)GATE * 1024 * 2);
  unsigned short* W1lo = (unsigned short*)take((size_t)GATE * 1024 * 2);

  // (TSTEPS+1)*ACTMAT ushorts = 33,619,968 B per buffer -> 2,101,248 16B units
  init_h<<<dim3(8208), dim3(256), 0, stream>>>(h0, h1);
  convert_x<<<dim3(16384), dim3(256), 0, stream>>>(x, xb);
  split_w<<<dim3(8192), dim3(256), 0, stream>>>(Wi0, Wh0, W0hi, W0lo);
  split_w<<<dim3(8192), dim3(256), 0, stream>>>(Wi1, Wh1, W1hi, W1lo);
  sublstm_persistent<<<dim3(128), dim3(256), 0, stream>>>(
      xb, h0, h1, W0hi, W0lo, W1hi, W1lo, bi0, bi1, out);
}

// Round 6
// 4718.666 us; speedup vs baseline: 1.1140x; 1.1140x over previous
//
#include <hip/hip_runtime.h>
#include <stdint.h>

#define TSTEPS 512
#define BATCH  64
#define HDIM   512
#define GATE   2048
#define ACTMAT (BATCH * HDIM)   // 32768 activations per timestep matrix
#define SENT   0xFFFFFFFFu      // f16 NaN-pair sentinel; |h|<1 so never produced

typedef __attribute__((ext_vector_type(8))) _Float16 f16x8;
typedef __attribute__((ext_vector_type(4))) float f32x4;
typedef __attribute__((ext_vector_type(4))) uint32_t u32x4;

__device__ __forceinline__ unsigned short f2h(float f) {
  union { _Float16 h; unsigned short u; } v;
  v.h = (_Float16)f;                                 // RNE f32->f16
  return v.u;
}
__device__ __forceinline__ float fsigmoid(float x) {
  return 1.0f / (1.0f + __expf(-x));
}

// ---------------- pre-kernels ----------------

// Fill h histories with sentinel; t=0 slice (first ACTMAT*2/16 units) = 0 (initial h).
__global__ void init_h(unsigned short* h0, unsigned short* h1) {
  size_t u = (size_t)blockIdx.x * blockDim.x + threadIdx.x;   // 16B unit index
  u32x4 v;
  if (u < (ACTMAT * 2 / 16)) v = (u32x4){0u, 0u, 0u, 0u};
  else                       v = (u32x4){SENT, SENT, SENT, SENT};
  ((u32x4*)h0)[u] = v;
  ((u32x4*)h1)[u] = v;
}

__global__ void convert_x(const float* __restrict__ x, unsigned short* __restrict__ xh) {
  size_t i = (size_t)(blockIdx.x * blockDim.x + threadIdx.x) * 4;
  float4 v = *(const float4*)(x + i);
  ushort4 o = make_ushort4(f2h(v.x), f2h(v.y), f2h(v.z), f2h(v.w));
  *(ushort4*)(xh + i) = o;
}

// Fuse [Wi | Wh] into [GATE][1024], single f16 panel (11 mantissa bits: rel err 2^-11).
__global__ void split_w(const float* __restrict__ Wi, const float* __restrict__ Wh,
                        unsigned short* __restrict__ Wf) {
  int i = blockIdx.x * blockDim.x + threadIdx.x;     // over GATE*1024
  int G = i >> 10, k = i & 1023;
  float w = (k < 512) ? Wi[((size_t)G << 9) + k] : Wh[((size_t)G << 9) + (k - 512)];
  Wf[i] = f2h(w);
}

// ---------------- persistent recurrence kernel ----------------
// 128 WGs x 256 threads: blockIdx>>6 = layer, blockIdx&63 = slice (8 h-cols, 32 gate rows).
// Transposed GEMM: D[n][b] = sum_k W[n][k]*Act[b][k] via mfma_f32_16x16x32_f16.
// Gate-row ordering G(n) = (n&3)*512 + j0 + 2*((n&15)>>2) + (n>>4): lane's 8 acc regs =
// all 4 gate quadrants of (b, j) and (b, j+1) -> zero-shuffle epilogue, one packed 4B
// h-store per lane. SYNC = DATA-AS-FLAG: h buffers pre-filled with SENT; producers just
// store packed dwords (L1/L2-bypass, meet at coherent MALL); consumers speculatively
// issue bypass loads, hide the round trip under independent MFMA work, then vmcnt(0)+
// sentinel check, re-issuing while any lane sees SENT. No flags/fences/barriers in loop.
// F16 single-panel weights: 64 KB LDS, 2 ds_read_b128 + 2 MFMA per CONSUME (was 4+4).

__global__ __launch_bounds__(256, 1)
void sublstm_persistent(const unsigned short* __restrict__ xh,
                        unsigned short* h0, unsigned short* h1,
                        const unsigned short* __restrict__ Wf0,
                        const unsigned short* __restrict__ Wf1,
                        const float* __restrict__ bi0, const float* __restrict__ bi1,
                        float* __restrict__ out)
{
  __shared__ unsigned short wlds[32][1024];          // 64 KiB: [n][k] f16 bits

  const int wg    = blockIdx.x;
  const int layer = wg >> 6;
  const int slice = wg & 63;
  const int j0    = slice << 3;                      // first owned h-column
  const int tid   = threadIdx.x;
  const int lane  = tid & 63;
  const int wv    = tid >> 6;                        // wave 0..3 (b-tile)

  const unsigned short* Wf = layer ? Wf1 : Wf0;
  const float* bi = layer ? bi1 : bi0;

  // stage weight slice into LDS (16B units, unit index XOR-swizzled by n&15)
  for (int idx = tid; idx < 4096; idx += 256) {
    int n = (idx >> 7) & 31;                         // local gate row
    int u = idx & 127;                               // 16B unit within row
    int G = ((n & 3) << 9) + j0 + ((((n & 15) >> 2)) << 1) + (n >> 4);
    const unsigned short* s = Wf + ((size_t)G << 10) + ((size_t)u << 3);
    *(uint4*)&wlds[n][(u ^ (n & 15)) << 3] = *(const uint4*)s;
  }
  __syncthreads();

  const int c15 = lane & 15;
  const int g4  = lane >> 4;
  const int n0 = c15, n1 = 16 + c15;
  const int sw = c15;                                // XOR swizzle key
  const int b    = (wv << 4) + c15;                  // batch row this lane owns
  const int jcol0 = j0 + (g4 << 1);                  // even h-col; pair (jcol0, jcol0+1)
  const size_t arow = (size_t)b * HDIM;
  const size_t hoff0 = arow + jcol0;

  const float b00 = bi[jcol0],        b01 = bi[512 + jcol0];
  const float b02 = bi[1024 + jcol0], b03 = bi[1536 + jcol0];
  const float b10 = bi[jcol0 + 1],        b11 = bi[512 + jcol0 + 1];
  const float b12 = bi[1024 + jcol0 + 1], b13 = bi[1536 + jcol0 + 1];

  float c0 = 0.0f, c1 = 0.0f;                        // cell state, in regs all 512 steps

#define CONSUME(R, KK, UB) do {                                                        \
    f16x8 a = __builtin_bit_cast(f16x8, (R));                                          \
    int u_ = ((UB) + ((KK) << 2) + g4) ^ sw;                                           \
    f16x8 w0 = *(const f16x8*)&wlds[n0][u_ << 3];                                      \
    f16x8 w1 = *(const f16x8*)&wlds[n1][u_ << 3];                                      \
    acc0 = __builtin_amdgcn_mfma_f32_16x16x32_f16(w0, a, acc0, 0, 0, 0);               \
    acc1 = __builtin_amdgcn_mfma_f32_16x16x32_f16(w1, a, acc1, 0, 0, 0);               \
  } while (0)

#define CONSUME_ALL(P, UB)                                                             \
    CONSUME(P##0, 0, UB);  CONSUME(P##1, 1, UB);  CONSUME(P##2, 2, UB);                \
    CONSUME(P##3, 3, UB);  CONSUME(P##4, 4, UB);  CONSUME(P##5, 5, UB);                \
    CONSUME(P##6, 6, UB);  CONSUME(P##7, 7, UB);  CONSUME(P##8, 8, UB);                \
    CONSUME(P##9, 9, UB);  CONSUME(P##10, 10, UB); CONSUME(P##11, 11, UB);             \
    CONSUME(P##12, 12, UB); CONSUME(P##13, 13, UB); CONSUME(P##14, 14, UB);            \
    CONSUME(P##15, 15, UB)

#define LD1(R, OFFTOK, HP)                                                             \
    asm volatile("global_load_dwordx4 %0, %1, off " OFFTOK " sc0 sc1"                  \
                 : "=v"(R) : "v"(HP) : "memory")

#define ISSUE16(HP, P) do {                                                            \
    LD1(P##0, "", HP);            LD1(P##1, "offset:64", HP);                          \
    LD1(P##2, "offset:128", HP);  LD1(P##3, "offset:192", HP);                         \
    LD1(P##4, "offset:256", HP);  LD1(P##5, "offset:320", HP);                         \
    LD1(P##6, "offset:384", HP);  LD1(P##7, "offset:448", HP);                         \
    LD1(P##8, "offset:512", HP);  LD1(P##9, "offset:576", HP);                         \
    LD1(P##10, "offset:640", HP); LD1(P##11, "offset:704", HP);                        \
    LD1(P##12, "offset:768", HP); LD1(P##13, "offset:832", HP);                        \
    LD1(P##14, "offset:896", HP); LD1(P##15, "offset:960", HP);                        \
  } while (0)

#define BAD1(R) ((R[0] == SENT) | (R[1] == SENT) | (R[2] == SENT) | (R[3] == SENT))

#define VALIDATE(HP, P) do {                                                           \
    for (;;) {                                                                         \
      asm volatile("s_waitcnt vmcnt(0)" ::: "memory");                                 \
      __builtin_amdgcn_sched_barrier(0);                                               \
      int bad_ = BAD1(P##0) | BAD1(P##1) | BAD1(P##2) | BAD1(P##3) |                   \
                 BAD1(P##4) | BAD1(P##5) | BAD1(P##6) | BAD1(P##7) |                   \
                 BAD1(P##8) | BAD1(P##9) | BAD1(P##10) | BAD1(P##11) |                 \
                 BAD1(P##12) | BAD1(P##13) | BAD1(P##14) | BAD1(P##15);                \
      if (!__any(bad_)) break;                                                         \
      ISSUE16(HP, P);                                                                  \
    }                                                                                  \
    __builtin_amdgcn_sched_barrier(0);                                                 \
  } while (0)

// x half: plain cached loads (xh is read-only input, L2-resident per XCD)
#define KHALF_X(AP) do {                                                               \
    const unsigned short* ap_ = (AP) + arow + (g4 << 3);                               \
    _Pragma("unroll")                                                                  \
    for (int kk = 0; kk < 16; ++kk) {                                                  \
      u32x4 rr = *(const u32x4*)(ap_ + (kk << 5));                                     \
      CONSUME(rr, kk, 0);                                                              \
    }                                                                                  \
  } while (0)

#define EPILOGUE(T) do {                                                               \
    unsigned short* hn = (layer ? h1 : h0) + (size_t)((T) + 1) * ACTMAT;               \
    float gi0 = fsigmoid(acc0[0] + b00), go0 = fsigmoid(acc0[1] + b01);                \
    float gz0 = fsigmoid(acc0[2] + b02), gf0 = fsigmoid(acc0[3] + b03);                \
    c0 = c0 * gf0 + gz0 - gi0;                                                         \
    float hv0 = fsigmoid(c0) - go0;                                                    \
    float gi1 = fsigmoid(acc1[0] + b10), go1 = fsigmoid(acc1[1] + b11);                \
    float gz1 = fsigmoid(acc1[2] + b12), gf1 = fsigmoid(acc1[3] + b13);                \
    c1 = c1 * gf1 + gz1 - gi1;                                                         \
    float hv1 = fsigmoid(c1) - go1;                                                    \
    uint32_t hw = (uint32_t)f2h(hv0) | ((uint32_t)f2h(hv1) << 16);                     \
    __hip_atomic_store((uint32_t*)(hn + hoff0), hw, __ATOMIC_RELAXED,                  \
                       __HIP_MEMORY_SCOPE_AGENT);                                      \
    if (layer) {                                                                       \
      float* outp = out + (size_t)(T) * ACTMAT;                                        \
      *(float2*)(outp + hoff0) = make_float2(hv0, hv1);                                \
    }                                                                                  \
  } while (0)

  if (layer == 0) {
    for (int t = 0; t < TSTEPS; ++t) {
      f32x4 acc0 = {}, acc1 = {};
      u32x4 ra0, ra1, ra2, ra3, ra4, ra5, ra6, ra7,
            ra8, ra9, ra10, ra11, ra12, ra13, ra14, ra15;
      const unsigned short* hp = h0 + (size_t)t * ACTMAT + arow + (g4 << 3);
      ISSUE16(hp, ra);                               // speculative: hide RT under x-half
      KHALF_X(xh + (size_t)t * ACTMAT);              // independent work (32 MFMAs)
      VALIDATE(hp, ra);                              // sentinel check, re-issue if stale
      CONSUME_ALL(ra, 64);
      EPILOGUE(t);
    }
  } else {
    for (int t = 0; t < TSTEPS; ++t) {
      f32x4 acc0 = {}, acc1 = {};
      u32x4 ra0, ra1, ra2, ra3, ra4, ra5, ra6, ra7,
            ra8, ra9, ra10, ra11, ra12, ra13, ra14, ra15;
      u32x4 rb0, rb1, rb2, rb3, rb4, rb5, rb6, rb7,
            rb8, rb9, rb10, rb11, rb12, rb13, rb14, rb15;
      const unsigned short* hpA = h1 + (size_t)t * ACTMAT + arow + (g4 << 3);
      const unsigned short* hpB = h0 + (size_t)(t + 1) * ACTMAT + arow + (g4 << 3);
      ISSUE16(hpA, ra);                              // own h1[t]: almost always landed
      ISSUE16(hpB, rb);                              // layer0's h0[t+1]: the late one
      VALIDATE(hpA, ra);
      CONSUME_ALL(ra, 64);                           // 32 MFMAs hide hpB's round trip
      VALIDATE(hpB, rb);
      CONSUME_ALL(rb, 0);
      EPILOGUE(t);
    }
  }
#undef CONSUME
#undef CONSUME_ALL
#undef LD1
#undef ISSUE16
#undef BAD1
#undef VALIDATE
#undef KHALF_X
#undef EPILOGUE
}

// ---------------- launch ----------------

extern "C" void kernel_launch(void* const* d_in, const int* in_sizes, int n_in,
                              void* d_out, int out_size, void* d_ws, size_t ws_size,
                              hipStream_t stream) {
  (void)in_sizes; (void)n_in; (void)out_size; (void)ws_size;
  const float* x   = (const float*)d_in[0];
  const float* Wi0 = (const float*)d_in[1];
  const float* bi0 = (const float*)d_in[2];
  const float* Wh0 = (const float*)d_in[3];
  const float* Wi1 = (const float*)d_in[4];
  const float* bi1 = (const float*)d_in[5];
  const float* Wh1 = (const float*)d_in[6];
  float* out = (float*)d_out;

  char* ws = (char*)d_ws;
  size_t off = 0;
  auto take = [&](size_t bytes) -> void* {
    void* p = ws + off;
    off += (bytes + 255) & ~(size_t)255;
    return p;
  };
  unsigned short* xh  = (unsigned short*)take((size_t)TSTEPS * ACTMAT * 2);        // 33.5 MB
  unsigned short* h0  = (unsigned short*)take((size_t)(TSTEPS + 1) * ACTMAT * 2);  // 33.6 MB
  unsigned short* h1  = (unsigned short*)take((size_t)(TSTEPS + 1) * ACTMAT * 2);  // 33.6 MB
  unsigned short* Wf0 = (unsigned short*)take((size_t)GATE * 1024 * 2);            // 4 MB
  unsigned short* Wf1 = (unsigned short*)take((size_t)GATE * 1024 * 2);            // 4 MB

  // (TSTEPS+1)*ACTMAT ushorts = 33,619,968 B per buffer -> 2,101,248 16B units
  init_h<<<dim3(8208), dim3(256), 0, stream>>>(h0, h1);
  convert_x<<<dim3(16384), dim3(256), 0, stream>>>(x, xh);
  split_w<<<dim3(8192), dim3(256), 0, stream>>>(Wi0, Wh0, Wf0);
  split_w<<<dim3(8192), dim3(256), 0, stream>>>(Wi1, Wh1, Wf1);
  sublstm_persistent<<<dim3(128), dim3(256), 0, stream>>>(
      xh, h0, h1, Wf0, Wf1, bi0, bi1, out);
}